// Round 1
// baseline (1023.821 us; speedup 1.0000x reference)
//
#include <hip/hip_runtime.h>

#define Bq 2
#define Lq 1024
#define Dq 1024
#define Hq 16
#define Eq 64
#define NDq 512
#define HDq 64

typedef __bf16 bf16x8 __attribute__((ext_vector_type(8)));
typedef float f32x4 __attribute__((ext_vector_type(4)));

__device__ __forceinline__ unsigned short f2bf(float x) {
    union { float f; unsigned u; } v; v.f = x;
    unsigned u = v.u;
    return (unsigned short)((u + 0x7FFFu + ((u >> 16) & 1u)) >> 16);
}
__device__ __forceinline__ float bf2f(unsigned short b) {
    union { unsigned u; float f; } v; v.u = ((unsigned)b) << 16;
    return v.f;
}
__device__ __forceinline__ float sigm(float x) { return 1.f / (1.f + __expf(-x)); }
__device__ __forceinline__ f32x4 mfma16(bf16x8 a, bf16x8 b, f32x4 c) {
    return __builtin_amdgcn_mfma_f32_16x16x32_bf16(a, b, c, 0, 0, 0);
}

// ---------------- weight convert + transpose: W fp32 [K][N] -> Wt bf16 [N][K]
__global__ __launch_bounds__(256) void k_wt(const float* __restrict__ W,
                                            unsigned short* __restrict__ Wt,
                                            int K, int N) {
    __shared__ unsigned short tile[32][33];
    int bk = blockIdx.x * 32, bn = blockIdx.y * 32;
    int t = threadIdx.x;
    int r = t >> 3, c4 = (t & 7) * 4;
    float4 v = *(const float4*)(W + (size_t)(bk + r) * N + bn + c4);
    tile[r][c4 + 0] = f2bf(v.x);
    tile[r][c4 + 1] = f2bf(v.y);
    tile[r][c4 + 2] = f2bf(v.z);
    tile[r][c4 + 3] = f2bf(v.w);
    __syncthreads();
    int nl = t >> 3, k4 = (t & 7) * 4;
    ushort4 o;
    o.x = tile[k4 + 0][nl];
    o.y = tile[k4 + 1][nl];
    o.z = tile[k4 + 2][nl];
    o.w = tile[k4 + 3][nl];
    *(ushort4*)(Wt + (size_t)(bn + nl) * K + bk + k4) = o;
}

// ---------------- LN(s)*g+b -> snb bf16 ; plus s -> sb bf16
__global__ __launch_bounds__(128) void k_lns(const float* __restrict__ s,
                                             const float* __restrict__ g,
                                             const float* __restrict__ be,
                                             unsigned short* __restrict__ snb,
                                             unsigned short* __restrict__ sb) {
    int row = blockIdx.x, t = threadIdx.x;
    float4 v = ((const float4*)(s + (size_t)row * NDq))[t];
    float sum = v.x + v.y + v.z + v.w;
    float sq = v.x * v.x + v.y * v.y + v.z * v.z + v.w * v.w;
    #pragma unroll
    for (int m = 1; m < 64; m <<= 1) { sum += __shfl_xor(sum, m); sq += __shfl_xor(sq, m); }
    __shared__ float red[4];
    int wv = t >> 6, ln = t & 63;
    if (ln == 0) { red[wv * 2] = sum; red[wv * 2 + 1] = sq; }
    __syncthreads();
    sum = red[0] + red[2]; sq = red[1] + red[3];
    float mean = sum * (1.f / NDq);
    float rstd = rsqrtf(sq * (1.f / NDq) - mean * mean + 1e-5f);
    int c0 = t * 4;
    ushort4 o, o2;
    o.x = f2bf((v.x - mean) * rstd * g[c0 + 0] + be[c0 + 0]);
    o.y = f2bf((v.y - mean) * rstd * g[c0 + 1] + be[c0 + 1]);
    o.z = f2bf((v.z - mean) * rstd * g[c0 + 2] + be[c0 + 2]);
    o.w = f2bf((v.w - mean) * rstd * g[c0 + 3] + be[c0 + 3]);
    o2.x = f2bf(v.x); o2.y = f2bf(v.y); o2.z = f2bf(v.z); o2.w = f2bf(v.w);
    ((ushort4*)(snb + (size_t)row * NDq))[t] = o;
    ((ushort4*)(sb + (size_t)row * NDq))[t] = o2;
}

// ---------------- LN(h) -> hn fp32
__global__ __launch_bounds__(256) void k_lnh(const float* __restrict__ hin,
                                             float* __restrict__ hn) {
    int row = blockIdx.x, t = threadIdx.x;
    float4 v = ((const float4*)(hin + (size_t)row * Dq))[t];
    float sum = v.x + v.y + v.z + v.w;
    float sq = v.x * v.x + v.y * v.y + v.z * v.z + v.w * v.w;
    #pragma unroll
    for (int m = 1; m < 64; m <<= 1) { sum += __shfl_xor(sum, m); sq += __shfl_xor(sq, m); }
    __shared__ float red[8];
    int wv = t >> 6, ln = t & 63;
    if (ln == 0) { red[wv * 2] = sum; red[wv * 2 + 1] = sq; }
    __syncthreads();
    sum = red[0] + red[2] + red[4] + red[6];
    sq = red[1] + red[3] + red[5] + red[7];
    float mean = sum * (1.f / Dq);
    float rstd = rsqrtf(sq * (1.f / Dq) - mean * mean + 1e-5f);
    float4 o;
    o.x = (v.x - mean) * rstd; o.y = (v.y - mean) * rstd;
    o.z = (v.z - mean) * rstd; o.w = (v.w - mean) * rstd;
    ((float4*)(hn + (size_t)row * Dq))[t] = o;
}

// ---------------- shared MFMA core: wave computes 64x32 tile, direct global frag loads
__device__ __forceinline__ void gemm_core(const unsigned short* __restrict__ A,
                                          const unsigned short* __restrict__ Bt,
                                          int K, int aRow0, int bCol0, f32x4 (&acc)[4][2]) {
    int lane = threadIdx.x & 63;
    int qd = lane >> 4, r16 = lane & 15;
    for (int k0 = 0; k0 < K; k0 += 32) {
        bf16x8 af[4], bfr[2];
        #pragma unroll
        for (int mi = 0; mi < 4; ++mi)
            af[mi] = *(const bf16x8*)(A + (size_t)(aRow0 + mi * 16 + r16) * K + k0 + qd * 8);
        #pragma unroll
        for (int ni = 0; ni < 2; ++ni)
            bfr[ni] = *(const bf16x8*)(Bt + (size_t)(bCol0 + ni * 16 + r16) * K + k0 + qd * 8);
        #pragma unroll
        for (int mi = 0; mi < 4; ++mi)
            #pragma unroll
            for (int ni = 0; ni < 2; ++ni)
                acc[mi][ni] = mfma16(af[mi], bfr[ni], acc[mi][ni]);
    }
}

// ---------------- h2 = sigmoid(sn@s1+b1)*hn + (sn@s2+b2)  -> h2b bf16
__global__ __launch_bounds__(256) void k_gemm_h2(const unsigned short* __restrict__ snb,
                                                 const unsigned short* __restrict__ s1t,
                                                 const unsigned short* __restrict__ s2t,
                                                 const float* __restrict__ s1b,
                                                 const float* __restrict__ s2b,
                                                 const float* __restrict__ hn,
                                                 unsigned short* __restrict__ h2b) {
    int w = threadIdx.x >> 6;
    int aRow0 = blockIdx.x * 128 + (w & 1) * 64;
    int nCol0 = blockIdx.y * 64 + (w >> 1) * 32;
    f32x4 acc1[4][2], acc2[4][2];
    f32x4 z = {0.f, 0.f, 0.f, 0.f};
    for (int mi = 0; mi < 4; ++mi) for (int ni = 0; ni < 2; ++ni) { acc1[mi][ni] = z; acc2[mi][ni] = z; }
    gemm_core(snb, s1t, NDq, aRow0, nCol0, acc1);
    gemm_core(snb, s2t, NDq, aRow0, nCol0, acc2);
    int lane = threadIdx.x & 63, qd = lane >> 4, r16 = lane & 15;
    #pragma unroll
    for (int mi = 0; mi < 4; ++mi)
        #pragma unroll
        for (int ni = 0; ni < 2; ++ni) {
            int col = nCol0 + ni * 16 + r16;
            float b1 = s1b[col], b2 = s2b[col];
            #pragma unroll
            for (int r = 0; r < 4; ++r) {
                int row = aRow0 + mi * 16 + qd * 4 + r;
                float a1 = acc1[mi][ni][r] + b1;
                float a2 = acc2[mi][ni][r] + b2;
                float val = sigm(a1) * hn[(size_t)row * Dq + col] + a2;
                h2b[(size_t)row * Dq + col] = f2bf(val);
            }
        }
}

// ---------------- qkvg: h2b @ {q,k,v,g}_w  (+bias, q scaled by 0.125, g sigmoided)
__global__ __launch_bounds__(256) void k_gemm_qkvg(const unsigned short* __restrict__ h2b,
                                                   const unsigned short* __restrict__ qt,
                                                   const unsigned short* __restrict__ kt,
                                                   const unsigned short* __restrict__ vt,
                                                   const unsigned short* __restrict__ gt,
                                                   const float* __restrict__ qbias,
                                                   const float* __restrict__ kbias,
                                                   const float* __restrict__ vbias,
                                                   const float* __restrict__ gbias,
                                                   unsigned short* __restrict__ qb,
                                                   unsigned short* __restrict__ kb,
                                                   unsigned short* __restrict__ vb,
                                                   unsigned short* __restrict__ gb) {
    int mat = blockIdx.y >> 4;
    int nloc0 = (blockIdx.y & 15) * 64;
    const unsigned short* Bt = (mat == 0) ? qt : (mat == 1) ? kt : (mat == 2) ? vt : gt;
    const float* bb = (mat == 0) ? qbias : (mat == 1) ? kbias : (mat == 2) ? vbias : gbias;
    unsigned short* ob = (mat == 0) ? qb : (mat == 1) ? kb : (mat == 2) ? vb : gb;
    int w = threadIdx.x >> 6;
    int aRow0 = blockIdx.x * 128 + (w & 1) * 64;
    int n0 = nloc0 + (w >> 1) * 32;
    f32x4 acc[4][2];
    f32x4 z = {0.f, 0.f, 0.f, 0.f};
    for (int mi = 0; mi < 4; ++mi) for (int ni = 0; ni < 2; ++ni) acc[mi][ni] = z;
    gemm_core(h2b, Bt, Dq, aRow0, n0, acc);
    int lane = threadIdx.x & 63, qd = lane >> 4, r16 = lane & 15;
    float scale = (mat == 0) ? 0.125f : 1.f;
    #pragma unroll
    for (int mi = 0; mi < 4; ++mi)
        #pragma unroll
        for (int ni = 0; ni < 2; ++ni) {
            int col = n0 + ni * 16 + r16;
            float bsv = bb[col];
            #pragma unroll
            for (int r = 0; r < 4; ++r) {
                int row = aRow0 + mi * 16 + qd * 4 + r;
                float val = (acc[mi][ni][r] + bsv) * scale;
                if (mat == 3) val = sigm(val);
                ob[(size_t)row * Dq + col] = f2bf(val);
            }
        }
}

// ---------------- pair bias: LN(p)*eg+eb @ e_w -> biasg bf16 [B][H][L][L]
__global__ __launch_bounds__(256) void k_bias(const float* __restrict__ p,
                                              const float* __restrict__ eg,
                                              const float* __restrict__ eb,
                                              const float* __restrict__ ew,
                                              unsigned short* __restrict__ biasg) {
    int j0 = blockIdx.x * 64;
    int i = blockIdx.y;
    int b = blockIdx.z;
    int w = threadIdx.x >> 6;
    int lane = threadIdx.x & 63;
    int qd = lane >> 4, r16 = lane & 15;
    int j = j0 + w * 16 + r16;
    const float* pr = p + (((size_t)b * Lq + i) * Lq + j) * Eq;
    float4 t0 = *(const float4*)(pr + qd * 8);
    float4 t1 = *(const float4*)(pr + qd * 8 + 4);
    float4 t2 = *(const float4*)(pr + 32 + qd * 8);
    float4 t3 = *(const float4*)(pr + 32 + qd * 8 + 4);
    float vals0[8] = {t0.x, t0.y, t0.z, t0.w, t1.x, t1.y, t1.z, t1.w};
    float vals1[8] = {t2.x, t2.y, t2.z, t2.w, t3.x, t3.y, t3.z, t3.w};
    float sum = 0.f, sq = 0.f;
    #pragma unroll
    for (int jj = 0; jj < 8; ++jj) {
        sum += vals0[jj] + vals1[jj];
        sq += vals0[jj] * vals0[jj] + vals1[jj] * vals1[jj];
    }
    sum += __shfl_xor(sum, 16); sum += __shfl_xor(sum, 32);
    sq += __shfl_xor(sq, 16);  sq += __shfl_xor(sq, 32);
    float mean = sum * (1.f / Eq);
    float rstd = rsqrtf(sq * (1.f / Eq) - mean * mean + 1e-5f);
    union Fr { unsigned short u[8]; bf16x8 v; } fa0, fa1, fb0, fb1;
    #pragma unroll
    for (int jj = 0; jj < 8; ++jj) {
        int k0i = qd * 8 + jj, k1i = 32 + qd * 8 + jj;
        fa0.u[jj] = f2bf((vals0[jj] - mean) * rstd * eg[k0i] + eb[k0i]);
        fa1.u[jj] = f2bf((vals1[jj] - mean) * rstd * eg[k1i] + eb[k1i]);
        fb0.u[jj] = f2bf(ew[k0i * Hq + r16]);
        fb1.u[jj] = f2bf(ew[k1i * Hq + r16]);
    }
    f32x4 c = {0.f, 0.f, 0.f, 0.f};
    c = mfma16(fa0.v, fb0.v, c);
    c = mfma16(fa1.v, fb1.v, c);
    __shared__ float bt[16][65];
    #pragma unroll
    for (int r = 0; r < 4; ++r)
        bt[r16][w * 16 + qd * 4 + r] = c[r];   // bt[h][j_local]
    __syncthreads();
    int t = threadIdx.x;
    int hh = t >> 4, jl = (t & 15) * 4;
    ushort4 o;
    o.x = f2bf(bt[hh][jl + 0]);
    o.y = f2bf(bt[hh][jl + 1]);
    o.z = f2bf(bt[hh][jl + 2]);
    o.w = f2bf(bt[hh][jl + 3]);
    *(ushort4*)(biasg + (((size_t)b * Hq + hh) * Lq + i) * Lq + j0 + jl) = o;
}

// ---------------- flash attention per wave: (b, h, 16 q-rows); y = g * softmax(S)@V
__global__ __launch_bounds__(64) void k_flash(const unsigned short* __restrict__ qb,
                                              const unsigned short* __restrict__ kb,
                                              const unsigned short* __restrict__ vb,
                                              const unsigned short* __restrict__ gb,
                                              const unsigned short* __restrict__ biasg,
                                              unsigned short* __restrict__ yb) {
    int i0 = blockIdx.x * 16;
    int h = blockIdx.y;
    int b = blockIdx.z;
    int lane = threadIdx.x;
    int qd = lane >> 4, r16 = lane & 15;
    bf16x8 qf0 = *(const bf16x8*)(qb + (size_t)(b * Lq + i0 + r16) * Dq + h * HDq + qd * 8);
    bf16x8 qf1 = *(const bf16x8*)(qb + (size_t)(b * Lq + i0 + r16) * Dq + h * HDq + 32 + qd * 8);
    f32x4 O[4];
    f32x4 z = {0.f, 0.f, 0.f, 0.f};
    O[0] = z; O[1] = z; O[2] = z; O[3] = z;
    float m[4], l[4];
    #pragma unroll
    for (int r = 0; r < 4; ++r) { m[r] = -1e30f; l[r] = 0.f; }
    const unsigned short* brow = biasg + ((size_t)(b * Hq + h) * Lq + i0) * Lq;
    __shared__ unsigned short Pl[16][40];
    for (int j0 = 0; j0 < Lq; j0 += 32) {
        f32x4 S0 = z, S1 = z;
        bf16x8 k00 = *(const bf16x8*)(kb + (size_t)(b * Lq + j0 + r16) * Dq + h * HDq + qd * 8);
        bf16x8 k01 = *(const bf16x8*)(kb + (size_t)(b * Lq + j0 + r16) * Dq + h * HDq + 32 + qd * 8);
        bf16x8 k10 = *(const bf16x8*)(kb + (size_t)(b * Lq + j0 + 16 + r16) * Dq + h * HDq + qd * 8);
        bf16x8 k11 = *(const bf16x8*)(kb + (size_t)(b * Lq + j0 + 16 + r16) * Dq + h * HDq + 32 + qd * 8);
        S0 = mfma16(qf0, k00, S0); S0 = mfma16(qf1, k01, S0);
        S1 = mfma16(qf0, k10, S1); S1 = mfma16(qf1, k11, S1);
        #pragma unroll
        for (int r = 0; r < 4; ++r) {
            S0[r] += bf2f(brow[(size_t)(qd * 4 + r) * Lq + j0 + r16]);
            S1[r] += bf2f(brow[(size_t)(qd * 4 + r) * Lq + j0 + 16 + r16]);
        }
        #pragma unroll
        for (int r = 0; r < 4; ++r) {
            float mx = fmaxf(S0[r], S1[r]);
            mx = fmaxf(mx, __shfl_xor(mx, 1));
            mx = fmaxf(mx, __shfl_xor(mx, 2));
            mx = fmaxf(mx, __shfl_xor(mx, 4));
            mx = fmaxf(mx, __shfl_xor(mx, 8));
            float mn = fmaxf(m[r], mx);
            float alpha = __expf(m[r] - mn);
            m[r] = mn;
            float p0 = __expf(S0[r] - mn), p1 = __expf(S1[r] - mn);
            S0[r] = p0; S1[r] = p1;
            float rs = p0 + p1;
            rs += __shfl_xor(rs, 1);
            rs += __shfl_xor(rs, 2);
            rs += __shfl_xor(rs, 4);
            rs += __shfl_xor(rs, 8);
            l[r] = l[r] * alpha + rs;
            O[0][r] *= alpha; O[1][r] *= alpha; O[2][r] *= alpha; O[3][r] *= alpha;
        }
        #pragma unroll
        for (int r = 0; r < 4; ++r) {
            Pl[qd * 4 + r][r16] = f2bf(S0[r]);
            Pl[qd * 4 + r][16 + r16] = f2bf(S1[r]);
        }
        __syncthreads();
        bf16x8 pf = *(const bf16x8*)(&Pl[r16][qd * 8]);
        #pragma unroll
        for (int db = 0; db < 4; ++db) {
            union Fr { unsigned short u[8]; bf16x8 v; } vf;
            #pragma unroll
            for (int jj = 0; jj < 8; ++jj)
                vf.u[jj] = vb[(size_t)(b * Lq + j0 + qd * 8 + jj) * Dq + h * HDq + db * 16 + r16];
            O[db] = mfma16(pf, vf.v, O[db]);
        }
        __syncthreads();
    }
    #pragma unroll
    for (int db = 0; db < 4; ++db)
        #pragma unroll
        for (int r = 0; r < 4; ++r) {
            int row = i0 + qd * 4 + r;
            int d = db * 16 + r16;
            float y = O[db][r] / l[r];
            float gg = bf2f(gb[(size_t)(b * Lq + row) * Dq + h * HDq + d]);
            yb[(size_t)(b * Lq + row) * Dq + h * HDq + d] = f2bf(y * gg);
        }
}

// ---------------- gate = sigmoid(s@op_w + op_b)  fp32
__global__ __launch_bounds__(256) void k_gate(const unsigned short* __restrict__ sb,
                                              const unsigned short* __restrict__ opt,
                                              const float* __restrict__ opb,
                                              float* __restrict__ gate) {
    int w = threadIdx.x >> 6;
    int aRow0 = blockIdx.x * 128 + (w & 1) * 64;
    int n0 = blockIdx.y * 64 + (w >> 1) * 32;
    f32x4 acc[4][2];
    f32x4 z = {0.f, 0.f, 0.f, 0.f};
    for (int mi = 0; mi < 4; ++mi) for (int ni = 0; ni < 2; ++ni) acc[mi][ni] = z;
    gemm_core(sb, opt, NDq, aRow0, n0, acc);
    int lane = threadIdx.x & 63, qd = lane >> 4, r16 = lane & 15;
    #pragma unroll
    for (int mi = 0; mi < 4; ++mi)
        #pragma unroll
        for (int ni = 0; ni < 2; ++ni) {
            int col = n0 + ni * 16 + r16;
            float bv = opb[col];
            #pragma unroll
            for (int r = 0; r < 4; ++r) {
                int row = aRow0 + mi * 16 + qd * 4 + r;
                gate[(size_t)row * Dq + col] = sigm(acc[mi][ni][r] + bv);
            }
        }
}

// ---------------- out = gate * (y@o_w + o_b)  fp32
__global__ __launch_bounds__(256) void k_out(const unsigned short* __restrict__ yb,
                                             const unsigned short* __restrict__ ot,
                                             const float* __restrict__ obv,
                                             const float* __restrict__ gate,
                                             float* __restrict__ out) {
    int w = threadIdx.x >> 6;
    int aRow0 = blockIdx.x * 128 + (w & 1) * 64;
    int n0 = blockIdx.y * 64 + (w >> 1) * 32;
    f32x4 acc[4][2];
    f32x4 z = {0.f, 0.f, 0.f, 0.f};
    for (int mi = 0; mi < 4; ++mi) for (int ni = 0; ni < 2; ++ni) acc[mi][ni] = z;
    gemm_core(yb, ot, Dq, aRow0, n0, acc);
    int lane = threadIdx.x & 63, qd = lane >> 4, r16 = lane & 15;
    #pragma unroll
    for (int mi = 0; mi < 4; ++mi)
        #pragma unroll
        for (int ni = 0; ni < 2; ++ni) {
            int col = n0 + ni * 16 + r16;
            float bv = obv[col];
            #pragma unroll
            for (int r = 0; r < 4; ++r) {
                int row = aRow0 + mi * 16 + qd * 4 + r;
                out[(size_t)row * Dq + col] = gate[(size_t)row * Dq + col] * (acc[mi][ni][r] + bv);
            }
        }
}

extern "C" void kernel_launch(void* const* d_in, const int* in_sizes, int n_in,
                              void* d_out, int out_size, void* d_ws, size_t ws_size,
                              hipStream_t stream) {
    const float* h     = (const float*)d_in[0];
    const float* p     = (const float*)d_in[1];
    const float* s     = (const float*)d_in[2];
    const float* sln_g = (const float*)d_in[3];
    const float* sln_b = (const float*)d_in[4];
    const float* s1_w  = (const float*)d_in[5];
    const float* s1_b  = (const float*)d_in[6];
    const float* s2_w  = (const float*)d_in[7];
    const float* s2_b  = (const float*)d_in[8];
    const float* q_w   = (const float*)d_in[9];
    const float* q_b   = (const float*)d_in[10];
    const float* k_w   = (const float*)d_in[11];
    const float* k_b   = (const float*)d_in[12];
    const float* v_w   = (const float*)d_in[13];
    const float* v_b   = (const float*)d_in[14];
    const float* eln_g = (const float*)d_in[15];
    const float* eln_b = (const float*)d_in[16];
    const float* e_w   = (const float*)d_in[17];
    const float* g_w   = (const float*)d_in[18];
    const float* g_b   = (const float*)d_in[19];
    const float* o_w   = (const float*)d_in[20];
    const float* o_b   = (const float*)d_in[21];
    const float* op_w  = (const float*)d_in[22];
    const float* op_b  = (const float*)d_in[23];
    float* out = (float*)d_out;

    unsigned char* w8 = (unsigned char*)d_ws;
    size_t off = 0;
    auto alloc = [&](size_t bytes) -> void* {
        void* r = w8 + off;
        off += (bytes + 255) & ~(size_t)255;
        return r;
    };
    const size_t M = (size_t)Bq * Lq;  // 2048
    unsigned short* s1t = (unsigned short*)alloc((size_t)NDq * Dq * 2);
    unsigned short* s2t = (unsigned short*)alloc((size_t)NDq * Dq * 2);
    unsigned short* qt  = (unsigned short*)alloc((size_t)Dq * Dq * 2);
    unsigned short* kt  = (unsigned short*)alloc((size_t)Dq * Dq * 2);
    unsigned short* vt  = (unsigned short*)alloc((size_t)Dq * Dq * 2);
    unsigned short* gt  = (unsigned short*)alloc((size_t)Dq * Dq * 2);
    unsigned short* ot  = (unsigned short*)alloc((size_t)Dq * Dq * 2);
    unsigned short* opt = (unsigned short*)alloc((size_t)NDq * Dq * 2);
    unsigned short* snb = (unsigned short*)alloc(M * NDq * 2);
    unsigned short* sb  = (unsigned short*)alloc(M * NDq * 2);
    float*          hn  = (float*)alloc(M * Dq * 4);
    unsigned short* h2b = (unsigned short*)alloc(M * Dq * 2);
    unsigned short* qb  = (unsigned short*)alloc(M * Dq * 2);
    unsigned short* kb  = (unsigned short*)alloc(M * Dq * 2);
    unsigned short* vb  = (unsigned short*)alloc(M * Dq * 2);
    unsigned short* gb  = (unsigned short*)alloc(M * Dq * 2);
    unsigned short* yb  = (unsigned short*)alloc(M * Dq * 2);
    float*          gate = (float*)alloc(M * Dq * 4);
    unsigned short* biasg = (unsigned short*)alloc((size_t)Bq * Hq * Lq * Lq * 2);
    (void)ws_size; (void)n_in; (void)in_sizes; (void)out_size;

    // weight transpose+convert
    k_wt<<<dim3(NDq / 32, Dq / 32), 256, 0, stream>>>(s1_w, s1t, NDq, Dq);
    k_wt<<<dim3(NDq / 32, Dq / 32), 256, 0, stream>>>(s2_w, s2t, NDq, Dq);
    k_wt<<<dim3(Dq / 32, Dq / 32), 256, 0, stream>>>(q_w, qt, Dq, Dq);
    k_wt<<<dim3(Dq / 32, Dq / 32), 256, 0, stream>>>(k_w, kt, Dq, Dq);
    k_wt<<<dim3(Dq / 32, Dq / 32), 256, 0, stream>>>(v_w, vt, Dq, Dq);
    k_wt<<<dim3(Dq / 32, Dq / 32), 256, 0, stream>>>(g_w, gt, Dq, Dq);
    k_wt<<<dim3(Dq / 32, Dq / 32), 256, 0, stream>>>(o_w, ot, Dq, Dq);
    k_wt<<<dim3(NDq / 32, Dq / 32), 256, 0, stream>>>(op_w, opt, NDq, Dq);
    // layernorms
    k_lns<<<dim3((int)M), 128, 0, stream>>>(s, sln_g, sln_b, snb, sb);
    k_lnh<<<dim3((int)M), 256, 0, stream>>>(h, hn);
    // h2
    k_gemm_h2<<<dim3(M / 128, Dq / 64), 256, 0, stream>>>(snb, s1t, s2t, s1_b, s2_b, hn, h2b);
    // qkvg
    k_gemm_qkvg<<<dim3(M / 128, 64), 256, 0, stream>>>(h2b, qt, kt, vt, gt,
                                                       q_b, k_b, v_b, g_b, qb, kb, vb, gb);
    // pair bias
    k_bias<<<dim3(Lq / 64, Lq, Bq), 256, 0, stream>>>(p, eln_g, eln_b, e_w, biasg);
    // attention
    k_flash<<<dim3(Lq / 16, Hq, Bq), 64, 0, stream>>>(qb, kb, vb, gb, biasg, yb);
    // gate and final projection
    k_gate<<<dim3(M / 128, Dq / 64), 256, 0, stream>>>(sb, opt, op_b, gate);
    k_out<<<dim3(M / 128, Dq / 64), 256, 0, stream>>>(yb, ot, o_b, gate, out);
}